// Round 17
// baseline (310.683 us; speedup 1.0000x reference)
//
#include <hip/hip_runtime.h>
#include <hip/hip_cooperative_groups.h>

namespace cg = cooperative_groups;

#define NEG_SLOPE 0.1f

typedef _Float16 h4_t __attribute__((ext_vector_type(4)));
typedef _Float16 h8_t __attribute__((ext_vector_type(8)));
typedef float f32x4 __attribute__((ext_vector_type(4)));

__device__ __forceinline__ unsigned lds_off(const void* p) {
    return (unsigned)(unsigned long long)p;
}

__device__ __forceinline__ void lgkm0() {
    asm volatile("s_waitcnt lgkmcnt(0)" ::: "memory");
    __builtin_amdgcn_sched_barrier(0);        // rule #18
}

__device__ __forceinline__ h4_t tr16(unsigned addr) {
    h4_t d;
    asm volatile("ds_read_b64_tr_b16 %0, %1" : "=v"(d) : "v"(addr) : "memory");
    return d;
}

#define RCH 4

// ===========================================================================
// Shared stage bodies (used by both the mega kernel and the fallback kernels)
// ===========================================================================
__device__ __forceinline__ void stage_prep_block(int b, int tid, void* smem,
    const float* __restrict__ W2, const float* __restrict__ W1,
    const float* __restrict__ a1W, const float* __restrict__ a2W,
    const float* __restrict__ Wp2, const float* __restrict__ x,
    const float* __restrict__ Wpca,
    _Float16* __restrict__ W2T, _Float16* __restrict__ W1T,
    _Float16* __restrict__ wpack, float* __restrict__ P)
{
    float (*tile)[33] = reinterpret_cast<float(*)[33]>(smem);
    float (*As)[33]   = reinterpret_cast<float(*)[33]>((char*)smem + 4224);
    float (*Bs)[64]   = reinterpret_cast<float(*)[64]>((char*)smem + 8448);

    if (b < 1024) {                         // W2T[n][k] = fp16 W2[k][n]
        const int n0 = (b & 31) * 32, k0 = (b >> 5) * 32;
        const int r = tid >> 3, c4 = (tid & 7) * 4;
        float4 v = *reinterpret_cast<const float4*>(&W2[(size_t)(k0 + r) * 1024 + n0 + c4]);
        tile[r][c4 + 0] = v.x; tile[r][c4 + 1] = v.y;
        tile[r][c4 + 2] = v.z; tile[r][c4 + 3] = v.w;
        __syncthreads();
        h4_t o;
        o[0] = (_Float16)tile[c4 + 0][r]; o[1] = (_Float16)tile[c4 + 1][r];
        o[2] = (_Float16)tile[c4 + 2][r]; o[3] = (_Float16)tile[c4 + 3][r];
        *reinterpret_cast<h4_t*>(&W2T[(size_t)(n0 + r) * 1024 + k0 + c4]) = o;
    } else if (b < 1088) {                  // W1T[n][k] = fp16 W1[k][n]
        const int b2 = b - 1024;
        const int n0 = (b2 & 31) * 32, k0 = (b2 >> 5) * 32;
        const int r = tid >> 3, c4 = (tid & 7) * 4;
        float4 v = *reinterpret_cast<const float4*>(&W1[(size_t)(k0 + r) * 1024 + n0 + c4]);
        tile[r][c4 + 0] = v.x; tile[r][c4 + 1] = v.y;
        tile[r][c4 + 2] = v.z; tile[r][c4 + 3] = v.w;
        __syncthreads();
        h4_t o;
        o[0] = (_Float16)tile[c4 + 0][r]; o[1] = (_Float16)tile[c4 + 1][r];
        o[2] = (_Float16)tile[c4 + 2][r]; o[3] = (_Float16)tile[c4 + 3][r];
        *reinterpret_cast<h4_t*>(&W1T[(size_t)(n0 + r) * 64 + k0 + c4]) = o;
    } else if (b < 3392) {                  // pack tail weights (K=32 B-frag)
        const int idx = (b - 1088) * 256 + tid;
        if (idx < 589824) {
            const int r = idx / 9216, qq = idx % 9216;
            float v;
            if (qq < 1024) {
                int nt = qq >> 8, rem = qq & 255, l = rem >> 2, j = rem & 3;
                int n = nt * 16 + (l & 15), k = (l >> 4) * 4 + j;
                v = a1W[(size_t)r * 1024 + k * 64 + n];
            } else if (qq < 5120) {
                int p = qq - 1024, kt = p >> 11, u = p & 2047, nt = u >> 9, s = u & 511,
                    l = s >> 3, j = s & 7;
                int n = nt * 16 + (l & 15), k = kt * 32 + (l >> 4) * 8 + j;
                v = a2W[(size_t)r * 4096 + k * 64 + n];
            } else {
                int p = qq - 5120, kt = p >> 11, u = p & 2047, nt = u >> 9, s = u & 511,
                    l = s >> 3, j = s & 7;
                int n = nt * 16 + (l & 15), k = kt * 32 + (l >> 4) * 8 + j;
                v = Wp2[((size_t)r * 64 + k) * 64 + n];
            }
            wpack[idx] = (_Float16)v;
        }
    } else {                                // split-K: t partials [8][4096][64]
        const int b2    = b - 3392;
        const int row0  = (b2 & 127) * 32;
        const int kbase = (b2 >> 7) * 128;
        const int r0    = (tid >> 4) * 2;
        const int c0    = (tid & 15) * 4;
        const int am    = tid >> 3;
        const int ak    = (tid & 7) * 4;
        float acc[2][4] = {};
#pragma unroll
        for (int kc = 0; kc < 128; kc += 32) {
            const int k0 = kbase + kc;
            float4 va = *reinterpret_cast<const float4*>(&x[(size_t)(row0 + am) * 1024 + k0 + ak]);
            As[ak + 0][am] = va.x; As[ak + 1][am] = va.y;
            As[ak + 2][am] = va.z; As[ak + 3][am] = va.w;
#pragma unroll
            for (int p = 0; p < 2; ++p) {
                int idx = tid + p * 256;
                int kk  = idx >> 4;
                int nq  = (idx & 15) * 4;
                *reinterpret_cast<float4*>(&Bs[kk][nq]) =
                    *reinterpret_cast<const float4*>(&Wpca[(size_t)(k0 + kk) * 64 + nq]);
            }
            __syncthreads();
#pragma unroll
            for (int k = 0; k < 32; ++k) {
                float a0 = As[k][r0], a1 = As[k][r0 + 1];
                float4 bv = *reinterpret_cast<const float4*>(&Bs[k][c0]);
                acc[0][0] = fmaf(a0, bv.x, acc[0][0]); acc[0][1] = fmaf(a0, bv.y, acc[0][1]);
                acc[0][2] = fmaf(a0, bv.z, acc[0][2]); acc[0][3] = fmaf(a0, bv.w, acc[0][3]);
                acc[1][0] = fmaf(a1, bv.x, acc[1][0]); acc[1][1] = fmaf(a1, bv.y, acc[1][1]);
                acc[1][2] = fmaf(a1, bv.z, acc[1][2]); acc[1][3] = fmaf(a1, bv.w, acc[1][3]);
            }
            __syncthreads();
        }
#pragma unroll
        for (int i = 0; i < 2; ++i) {
            float4 o; o.x = acc[i][0]; o.y = acc[i][1]; o.z = acc[i][2]; o.w = acc[i][3];
            *reinterpret_cast<float4*>(
                &P[((size_t)(b2 >> 7) * 4096 + row0 + r0 + i) * 64 + c0]) = o;
        }
    }
}

__device__ __forceinline__ void stage_combine_block(int vb, int tid,
    const float* __restrict__ P, const float* __restrict__ bpca,
    const float* __restrict__ bp2, const float* __restrict__ Wl,
    const float* __restrict__ bl,
    _Float16* __restrict__ t16, float* __restrict__ out)
{
    const int idx = vb * 256 + tid;
    float s = bpca[idx & 63];
#pragma unroll
    for (int c = 0; c < 8; ++c)
        s += P[(size_t)c * 262144 + idx];
    t16[idx] = (_Float16)s;
    if (idx < 4096) {
        float cst = bl[0];
#pragma unroll
        for (int f = 0; f < 64; ++f)
            cst += bp2[f] * Wl[f];
        out[idx] = cst;
    }
}

__device__ __forceinline__ void stage_k2_block(int wg, int tid, void* smem,
    const _Float16* __restrict__ A, const _Float16* __restrict__ BT,
    const float* __restrict__ bias, _Float16* __restrict__ C)
{
    _Float16* As = (_Float16*)smem;              // 128*64 fp16 = 16KB
    _Float16* Bs = (_Float16*)((char*)smem + 16384);
    const int l   = tid & 63;
    const int w   = tid >> 6;
    const int wm  = w >> 1;
    const int wn  = w & 1;
    const int bm0 = (wg >> 3) * 128;
    const int bn0 = (wg & 7) * 128;
    const int fr  = l & 15;
    const int fg  = l >> 4;
    const int srow  = l >> 3;
    const int sslot = l & 7;

#pragma unroll
    for (int i = 0; i < 4; ++i) {
        const int r0   = w * 32 + i * 8;
        const int rowA = r0 + srow;
        const int slot = sslot ^ (rowA & 7);
        __builtin_amdgcn_global_load_lds(
            (const __attribute__((address_space(1))) void*)&A[(size_t)(bm0 + rowA) * 64 + slot * 8],
            (__attribute__((address_space(3))) void*)&As[r0 * 64], 16, 0, 0);
        __builtin_amdgcn_global_load_lds(
            (const __attribute__((address_space(1))) void*)&BT[(size_t)(bn0 + rowA) * 64 + slot * 8],
            (__attribute__((address_space(3))) void*)&Bs[r0 * 64], 16, 0, 0);
    }
    __syncthreads();

    f32x4 acc[4][4] = {};
#pragma unroll
    for (int ks = 0; ks < 2; ++ks) {
        h8_t af[4], bf[4];
#pragma unroll
        for (int mt = 0; mt < 4; ++mt) {
            int row = wm * 64 + mt * 16 + fr;
            int sg  = ks * 4 + fg;
            af[mt] = *reinterpret_cast<const h8_t*>(&As[row * 64 + ((sg ^ (row & 7)) << 3)]);
        }
#pragma unroll
        for (int nt = 0; nt < 4; ++nt) {
            int row = wn * 64 + nt * 16 + fr;
            int sg  = ks * 4 + fg;
            bf[nt] = *reinterpret_cast<const h8_t*>(&Bs[row * 64 + ((sg ^ (row & 7)) << 3)]);
        }
#pragma unroll
        for (int mt = 0; mt < 4; ++mt)
#pragma unroll
            for (int nt = 0; nt < 4; ++nt)
                acc[mt][nt] = __builtin_amdgcn_mfma_f32_16x16x32_f16(af[mt], bf[nt],
                                                                     acc[mt][nt], 0, 0, 0);
    }

#pragma unroll
    for (int nt = 0; nt < 4; ++nt) {
        const int col = bn0 + wn * 64 + nt * 16 + fr;
        const float bv = bias[col];
#pragma unroll
        for (int mt = 0; mt < 4; ++mt)
#pragma unroll
            for (int rg = 0; rg < 4; ++rg) {
                const int row = bm0 + wm * 64 + mt * 16 + fg * 4 + rg;
                float v = acc[mt][nt][rg] + bv;
                C[(size_t)row * 1024 + col] = (_Float16)fmaxf(v, NEG_SLOPE * v);
            }
    }
}

__device__ __forceinline__ void stage_k3_block(int wg, int tid, void* smem,
    const _Float16* __restrict__ A, const _Float16* __restrict__ BT,
    const float* __restrict__ bias, _Float16* __restrict__ h2t)
{
    _Float16* As = (_Float16*)smem;              // 64*64 fp16 = 8KB
    _Float16* Bs = (_Float16*)((char*)smem + 8192);
    const int l   = tid & 63;
    const int w   = tid >> 6;
    const int wm  = w >> 1;
    const int wn  = w & 1;
    const int bm0 = (wg >> 3) * 64;
    const int bn0 = (wg & 7) * 128;
    const int fr  = l & 15;
    const int fg  = l >> 4;
    const int srow  = l >> 3;
    const int sslot = l & 7;

    f32x4 acc[2][4] = {};

    for (int k0 = 0; k0 < 1024; k0 += 64) {
#pragma unroll
        for (int i = 0; i < 2; ++i) {
            const int r0   = w * 16 + i * 8;
            const int rowA = r0 + srow;
            const int slot = sslot ^ (rowA & 7);
            __builtin_amdgcn_global_load_lds(
                (const __attribute__((address_space(1))) void*)&A[(size_t)(bm0 + rowA) * 1024 + k0 + slot * 8],
                (__attribute__((address_space(3))) void*)&As[r0 * 64], 16, 0, 0);
        }
#pragma unroll
        for (int i = 0; i < 4; ++i) {
            const int r0   = w * 32 + i * 8;
            const int rowB = r0 + srow;
            const int slot = sslot ^ (rowB & 7);
            __builtin_amdgcn_global_load_lds(
                (const __attribute__((address_space(1))) void*)&BT[(size_t)(bn0 + rowB) * 1024 + k0 + slot * 8],
                (__attribute__((address_space(3))) void*)&Bs[r0 * 64], 16, 0, 0);
        }
        __syncthreads();

#pragma unroll
        for (int ks = 0; ks < 2; ++ks) {
            h8_t af[2], bf[4];
#pragma unroll
            for (int mt = 0; mt < 2; ++mt) {
                int row = wm * 32 + mt * 16 + fr;
                int sg  = ks * 4 + fg;
                af[mt] = *reinterpret_cast<const h8_t*>(&As[row * 64 + ((sg ^ (row & 7)) << 3)]);
            }
#pragma unroll
            for (int nt = 0; nt < 4; ++nt) {
                int row = wn * 64 + nt * 16 + fr;
                int sg  = ks * 4 + fg;
                bf[nt] = *reinterpret_cast<const h8_t*>(&Bs[row * 64 + ((sg ^ (row & 7)) << 3)]);
            }
#pragma unroll
            for (int mt = 0; mt < 2; ++mt)
#pragma unroll
                for (int nt = 0; nt < 4; ++nt)
                    acc[mt][nt] = __builtin_amdgcn_mfma_f32_16x16x32_f16(af[mt], bf[nt],
                                                                         acc[mt][nt], 0, 0, 0);
        }
        __syncthreads();
    }

    const int rblk0 = (bm0 >> 4) + wm * 2;
    const int cblk0 = (bn0 >> 4) + wn * 4;
#pragma unroll
    for (int nt = 0; nt < 4; ++nt) {
        const int col = bn0 + wn * 64 + nt * 16 + fr;
        const float bv = bias[col];
#pragma unroll
        for (int mt = 0; mt < 2; ++mt) {
            h4_t pk;
#pragma unroll
            for (int r = 0; r < 4; ++r) {
                float v = acc[mt][nt][r] + bv;
                pk[r] = (_Float16)fmaxf(v, NEG_SLOPE * v);
            }
            *reinterpret_cast<h4_t*>(
                &h2t[(((size_t)(cblk0 + nt) * 256 + rblk0 + mt) * 16 + fr) * 16 + fg * 4]) = pk;
        }
    }
}

__device__ __forceinline__ void stage_tail_block(int bx, int by, int tid, void* smem,
    const _Float16* __restrict__ h2t, const _Float16* __restrict__ wpack,
    const float* __restrict__ a1b, const float* __restrict__ a1bias,
    const float* __restrict__ a2b, const float* __restrict__ a2bias,
    const float* __restrict__ Wl, float* __restrict__ out)
{
    _Float16* stg  = (_Float16*)smem;            // 2 x 11264 fp16 = 44KB
    _Float16* actb = (_Float16*)((char*)smem + 45056);  // 16KB
    const int l = tid & 63, w = tid >> 6;
    const int c = l & 15, q = l >> 4;
    const int row0  = bx * 128;
    const int rbase = by * RCH;
    const float b1s = a1bias[0], b2s = a2bias[0];

    const unsigned trl   = l * 8;
    const unsigned abase = lds_off(&actb[w * 2048]);

    float b1v[RCH][4], b2v[RCH][4];
#pragma unroll
    for (int rl = 0; rl < RCH; ++rl)
#pragma unroll
        for (int nt = 0; nt < 4; ++nt) {
            b1v[rl][nt] = a1b[(rbase + rl) * 64 + nt * 16 + c] + b1s;
            b2v[rl][nt] = a2b[(rbase + rl) * 64 + nt * 16 + c] + b2s;
        }
    float wlv[4];
#pragma unroll
    for (int nt = 0; nt < 4; ++nt) wlv[nt] = Wl[nt * 16 + c];

    auto STAGE = [&](int rl, int b) {
        const int r = rbase + rl;
        const _Float16* hsrc = h2t + ((size_t)r * 256 + bx * 8) * 256;
        const _Float16* wsrc = wpack + (size_t)r * 9216;
#pragma unroll
        for (int i = 0; i < 6; ++i) {
            const int ch = i * 4 + w;
            if (ch < 22) {
                const _Float16* src = (ch < 4) ? (hsrc + ch * 512) : (wsrc + (ch - 4) * 512);
                __builtin_amdgcn_global_load_lds(
                    (const __attribute__((address_space(1))) void*)(src + l * 8),
                    (__attribute__((address_space(3))) void*)&stg[b * 11264 + ch * 512], 16, 0, 0);
            }
        }
    };

    STAGE(0, 0);
    __syncthreads();

    f32x4 accT[2][4] = {};
    int cur = 0;

#pragma unroll
    for (int rl = 0; rl < RCH; ++rl) {
        if (rl + 1 < RCH) STAGE(rl + 1, cur ^ 1);

        const _Float16* sp = &stg[cur * 11264];
        const unsigned sbytes = lds_off(sp);

        // ---- phase A
        h4_t ha0 = tr16(sbytes + (unsigned)(w) * 512 + trl);
        h4_t ha1 = tr16(sbytes + (unsigned)(w + 4) * 512 + trl);
        lgkm0();
        f32x4 pa[2][4];
#pragma unroll
        for (int nt = 0; nt < 4; ++nt) {
            h4_t bf = *reinterpret_cast<const h4_t*>(&sp[2048 + nt * 256 + l * 4]);
            pa[0][nt] = __builtin_amdgcn_mfma_f32_16x16x16f16(ha0, bf, (f32x4){0.f,0.f,0.f,0.f}, 0, 0, 0);
            pa[1][nt] = __builtin_amdgcn_mfma_f32_16x16x16f16(ha1, bf, (f32x4){0.f,0.f,0.f,0.f}, 0, 0, 0);
        }
#pragma unroll
        for (int j = 0; j < 2; ++j)
#pragma unroll
            for (int nt = 0; nt < 4; ++nt) {
                h4_t pk;
#pragma unroll
                for (int rg = 0; rg < 4; ++rg) {
                    float v = pa[j][nt][rg] + b1v[rl][nt];
                    pk[rg] = (_Float16)fmaxf(v, NEG_SLOPE * v);
                }
                const int kk = nt * 16 + c;
                const int hh = (kk >> 2) & 1;
                const int kp = (kk & 3) | ((kk >> 3) << 2);
                *reinterpret_cast<h4_t*>(&actb[w * 2048 + j * 1024 + hh * 512 + kp * 16 + q * 4]) = pk;
            }
        lgkm0();

        // ---- phase B
        h8_t afB[2][2];
#pragma unroll
        for (int j = 0; j < 2; ++j)
#pragma unroll
            for (int kt = 0; kt < 2; ++kt) {
                h4_t lo = tr16(abase + (unsigned)(j * 2048 + kt * 512) + trl);
                h4_t hi = tr16(abase + (unsigned)(j * 2048 + 1024 + kt * 512) + trl);
                afB[j][kt] = __builtin_shufflevector(lo, hi, 0, 1, 2, 3, 4, 5, 6, 7);
            }
        lgkm0();
        f32x4 pb[2][4] = {};
#pragma unroll
        for (int kt = 0; kt < 2; ++kt)
#pragma unroll
            for (int nt = 0; nt < 4; ++nt) {
                h8_t bf = *reinterpret_cast<const h8_t*>(&sp[3072 + kt * 2048 + nt * 512 + l * 8]);
                pb[0][nt] = __builtin_amdgcn_mfma_f32_16x16x32_f16(afB[0][kt], bf, pb[0][nt], 0, 0, 0);
                pb[1][nt] = __builtin_amdgcn_mfma_f32_16x16x32_f16(afB[1][kt], bf, pb[1][nt], 0, 0, 0);
            }
#pragma unroll
        for (int j = 0; j < 2; ++j)
#pragma unroll
            for (int nt = 0; nt < 4; ++nt) {
                h4_t pk;
#pragma unroll
                for (int rg = 0; rg < 4; ++rg) {
                    float v = pb[j][nt][rg] + b2v[rl][nt];
                    pk[rg] = (_Float16)fmaxf(v, NEG_SLOPE * v);
                }
                const int kk = nt * 16 + c;
                const int hh = (kk >> 2) & 1;
                const int kp = (kk & 3) | ((kk >> 3) << 2);
                *reinterpret_cast<h4_t*>(&actb[w * 2048 + j * 1024 + hh * 512 + kp * 16 + q * 4]) = pk;
            }
        lgkm0();

        // ---- phase C
        h8_t afC[2][2];
#pragma unroll
        for (int j = 0; j < 2; ++j)
#pragma unroll
            for (int kt = 0; kt < 2; ++kt) {
                h4_t lo = tr16(abase + (unsigned)(j * 2048 + kt * 512) + trl);
                h4_t hi = tr16(abase + (unsigned)(j * 2048 + 1024 + kt * 512) + trl);
                afC[j][kt] = __builtin_shufflevector(lo, hi, 0, 1, 2, 3, 4, 5, 6, 7);
            }
        lgkm0();
#pragma unroll
        for (int kt = 0; kt < 2; ++kt)
#pragma unroll
            for (int nt = 0; nt < 4; ++nt) {
                h8_t bf = *reinterpret_cast<const h8_t*>(&sp[7168 + kt * 2048 + nt * 512 + l * 8]);
                accT[0][nt] = __builtin_amdgcn_mfma_f32_16x16x32_f16(afC[0][kt], bf, accT[0][nt], 0, 0, 0);
                accT[1][nt] = __builtin_amdgcn_mfma_f32_16x16x32_f16(afC[1][kt], bf, accT[1][nt], 0, 0, 0);
            }

        __syncthreads();
        cur ^= 1;
    }

    // ---- epilogue: per-row dot with Wl, lane-reduce, atomicAdd
#pragma unroll
    for (int j = 0; j < 2; ++j)
#pragma unroll
        for (int rg = 0; rg < 4; ++rg) {
            float s = accT[j][0][rg] * wlv[0] + accT[j][1][rg] * wlv[1] +
                      accT[j][2][rg] * wlv[2] + accT[j][3][rg] * wlv[3];
            s += __shfl_xor(s, 1);
            s += __shfl_xor(s, 2);
            s += __shfl_xor(s, 4);
            s += __shfl_xor(s, 8);
            if (c == 0) {
                const int row = row0 + (w + 4 * j) * 16 + q * 4 + rg;
                atomicAdd(&out[row], s);
            }
        }
}

// ===========================================================================
// Cooperative mega kernel (launch_bounds min-occupancy 2 waves/EU => 2 WG/CU
// => 512 blocks co-resident). NO aliased restrict pointers.
// ===========================================================================
__global__ __launch_bounds__(256, 2) void mega(
    const float* __restrict__ W2,  const float* __restrict__ W1,
    const float* __restrict__ a1W, const float* __restrict__ a2W,
    const float* __restrict__ Wp2, const float* __restrict__ x,
    const float* __restrict__ Wpca, const float* __restrict__ bpca,
    const float* __restrict__ b1,  const float* __restrict__ b2,
    const float* __restrict__ a1b, const float* __restrict__ a1bias,
    const float* __restrict__ a2b, const float* __restrict__ a2bias,
    const float* __restrict__ bp2, const float* __restrict__ Wl,
    const float* __restrict__ bl,
    _Float16* __restrict__ W2T, _Float16* __restrict__ W1T,
    _Float16* __restrict__ wpack, float* __restrict__ P,
    _Float16* __restrict__ t16, _Float16* __restrict__ h1h,
    _Float16* __restrict__ h2t, float* __restrict__ out)
{
    __shared__ alignas(16) char smem[61440];   // 60KB union
    cg::grid_group gridg = cg::this_grid();
    const int wg  = blockIdx.x;
    const int tid = threadIdx.x;

    // stage 0: prep + splitk
    for (int b = wg; b < 4416; b += 512) {
        stage_prep_block(b, tid, smem, W2, W1, a1W, a2W, Wp2, x, Wpca,
                         W2T, W1T, wpack, P);
        __syncthreads();
    }
    gridg.sync();

    // stage 1: combine t -> fp16; init out
    for (int vb = wg; vb < 1024; vb += 512)
        stage_combine_block(vb, tid, P, bpca, bp2, Wl, bl, t16, out);
    gridg.sync();

    // stage 2: K2
    if (wg < 256)
        stage_k2_block(wg, tid, smem, t16, W1T, b1, h1h);
    gridg.sync();

    // stage 3: K3
    stage_k3_block(wg, tid, smem, h1h, W2T, b2, h2t);
    gridg.sync();

    // stage 4: fused tail
    stage_tail_block(wg & 31, wg >> 5, tid, smem, h2t, wpack,
                     a1b, a1bias, a2b, a2bias, Wl, out);
}

// ===========================================================================
// Fallback kernels (= passing round-15 build, via the shared stage bodies)
// ===========================================================================
__global__ __launch_bounds__(256) void fb_prep_splitk(
    const float* __restrict__ W2, const float* __restrict__ W1,
    const float* __restrict__ a1W, const float* __restrict__ a2W,
    const float* __restrict__ Wp2, const float* __restrict__ x,
    const float* __restrict__ Wpca,
    _Float16* __restrict__ W2T, _Float16* __restrict__ W1T,
    _Float16* __restrict__ wpack, float* __restrict__ P)
{
    __shared__ alignas(16) char smem[16640];
    stage_prep_block(blockIdx.x, threadIdx.x, smem, W2, W1, a1W, a2W, Wp2, x, Wpca,
                     W2T, W1T, wpack, P);
}

__global__ __launch_bounds__(256) void fb_combine(
    const float* __restrict__ P, const float* __restrict__ bpca,
    const float* __restrict__ bp2, const float* __restrict__ Wl,
    const float* __restrict__ bl,
    _Float16* __restrict__ t16, float* __restrict__ out)
{
    stage_combine_block(blockIdx.x, threadIdx.x, P, bpca, bp2, Wl, bl, t16, out);
}

__global__ __launch_bounds__(256) void fb_k2(const _Float16* __restrict__ A,
                                             const _Float16* __restrict__ BT,
                                             const float* __restrict__ bias,
                                             _Float16* __restrict__ C)
{
    __shared__ alignas(16) char smem[32768];
    stage_k2_block(blockIdx.x, threadIdx.x, smem, A, BT, bias, C);
}

__global__ __launch_bounds__(256) void fb_k3(const _Float16* __restrict__ A,
                                             const _Float16* __restrict__ BT,
                                             const float* __restrict__ bias,
                                             _Float16* __restrict__ h2t)
{
    __shared__ alignas(16) char smem[24576];
    stage_k3_block(blockIdx.x, threadIdx.x, smem, A, BT, bias, h2t);
}

__global__ __launch_bounds__(256) void fb_tail(const _Float16* __restrict__ h2t,
                                               const _Float16* __restrict__ wpack,
                                               const float* __restrict__ a1b,
                                               const float* __restrict__ a1bias,
                                               const float* __restrict__ a2b,
                                               const float* __restrict__ a2bias,
                                               const float* __restrict__ Wl,
                                               float* __restrict__ out)
{
    __shared__ alignas(16) char smem[61440];
    stage_tail_block(blockIdx.x & 31, blockIdx.x >> 5, threadIdx.x, smem,
                     h2t, wpack, a1b, a1bias, a2b, a2bias, Wl, out);
}

// ---------------------------------------------------------------------------
extern "C" void kernel_launch(void* const* d_in, const int* in_sizes, int n_in,
                              void* d_out, int out_size, void* d_ws, size_t ws_size,
                              hipStream_t stream)
{
    const float* x      = (const float*)d_in[0];
    const float* Wpca   = (const float*)d_in[1];
    const float* bpca   = (const float*)d_in[2];
    const float* W1     = (const float*)d_in[3];
    const float* b1     = (const float*)d_in[4];
    const float* W2     = (const float*)d_in[5];
    const float* b2     = (const float*)d_in[6];
    const float* a1W    = (const float*)d_in[7];
    const float* a1b    = (const float*)d_in[8];
    const float* a1bias = (const float*)d_in[9];
    const float* a2W    = (const float*)d_in[10];
    const float* a2b    = (const float*)d_in[11];
    const float* a2bias = (const float*)d_in[12];
    const float* Wp2    = (const float*)d_in[13];
    const float* bp2    = (const float*)d_in[14];
    const float* Wl     = (const float*)d_in[15];
    const float* bl     = (const float*)d_in[16];
    float* out = (float*)d_out;

    // workspace layout (bytes) — fully disjoint (NO aliasing):
    //   t16 [0,0.5M)  h1h [1M,9M)  h2t [9M,17M)  W2T [17M,19M)
    //   wpack [19M,20.13M)  W1T [21M,21.13M)  tpart [22M,30M)
    char* wsb = (char*)d_ws;
    _Float16* t16   = (_Float16*)(wsb);
    _Float16* h1h   = (_Float16*)(wsb + (1ull  << 20));
    _Float16* h2t   = (_Float16*)(wsb + (9ull  << 20));
    _Float16* W2T   = (_Float16*)(wsb + (17ull << 20));
    _Float16* wpack = (_Float16*)(wsb + (19ull << 20));
    _Float16* W1T   = (_Float16*)(wsb + (21ull << 20));
    float*    tpart = (float*)   (wsb + (22ull << 20));

    void* args[] = {
        (void*)&W2, (void*)&W1, (void*)&a1W, (void*)&a2W, (void*)&Wp2,
        (void*)&x,  (void*)&Wpca, (void*)&bpca, (void*)&b1, (void*)&b2,
        (void*)&a1b, (void*)&a1bias, (void*)&a2b, (void*)&a2bias,
        (void*)&bp2, (void*)&Wl, (void*)&bl,
        (void*)&W2T, (void*)&W1T, (void*)&wpack, (void*)&tpart,
        (void*)&t16, (void*)&h1h, (void*)&h2t, (void*)&out
    };
    hipError_t e = hipLaunchCooperativeKernel((void*)mega, dim3(512), dim3(256),
                                              args, 0, stream);
    if (e != hipSuccess) {
        // deterministic fallback: the proven 5-kernel pipeline (same math)
        fb_prep_splitk<<<dim3(4416), 256, 0, stream>>>(W2, W1, a1W, a2W, Wp2, x, Wpca,
                                                       W2T, W1T, wpack, tpart);
        fb_combine<<<dim3(1024), 256, 0, stream>>>(tpart, bpca, bp2, Wl, bl, t16, out);
        fb_k2<<<dim3(256), 256, 0, stream>>>(t16, W1T, b1, h1h);
        fb_k3<<<dim3(512), 256, 0, stream>>>(h1h, W2T, b2, h2t);
        fb_tail<<<dim3(512), 256, 0, stream>>>(h2t, wpack, a1b, a1bias,
                                               a2b, a2bias, Wl, out);
    }
}

// Round 19
// 62.586 us; speedup vs baseline: 4.9641x; 4.9641x over previous
//
#include <hip/hip_runtime.h>

#define NEG_SLOPE 0.1f

typedef _Float16 h4_t __attribute__((ext_vector_type(4)));
typedef _Float16 h8_t __attribute__((ext_vector_type(8)));
typedef float f32x4 __attribute__((ext_vector_type(4)));

__device__ __forceinline__ unsigned lds_off(const void* p) {
    return (unsigned)(unsigned long long)p;
}

__device__ __forceinline__ void lgkm0() {
    asm volatile("s_waitcnt lgkmcnt(0)" ::: "memory");
    __builtin_amdgcn_sched_barrier(0);        // rule #18
}

__device__ __forceinline__ h4_t tr16(unsigned addr) {
    h4_t d;
    asm volatile("ds_read_b64_tr_b16 %0, %1" : "=v"(d) : "v"(addr) : "memory");
    return d;
}

#define RCH 4

// ---------------------------------------------------------------------------
// K0 prep: W2T + wpack + WfT=(Wpca@W1)^T fp16 + x->fp16 + bfused + out init.
// blocks: [0,1024) W2T | [1024,3328) wpack | [3328,4352) WfT |
//         [4352,6400) x16 | 6400 bfused | [6401,6417) out-init.
// ---------------------------------------------------------------------------
__global__ __launch_bounds__(256) void prep2(const float* __restrict__ W2,
                                             const float* __restrict__ W1,
                                             const float* __restrict__ Wpca,
                                             const float* __restrict__ bpca,
                                             const float* __restrict__ b1,
                                             const float* __restrict__ a1W,
                                             const float* __restrict__ a2W,
                                             const float* __restrict__ Wp2,
                                             const float* __restrict__ x,
                                             const float* __restrict__ bp2,
                                             const float* __restrict__ Wl,
                                             const float* __restrict__ bl,
                                             _Float16* __restrict__ W2T,
                                             _Float16* __restrict__ wpack,
                                             _Float16* __restrict__ WfT,
                                             _Float16* __restrict__ x16,
                                             float* __restrict__ bfused,
                                             float* __restrict__ out)
{
    __shared__ alignas(16) char smem[17408];
    const int b   = blockIdx.x;
    const int tid = threadIdx.x;

    if (b < 1024) {                         // W2T[n][k] = fp16 W2[k][n]
        float (*tile)[33] = reinterpret_cast<float(*)[33]>(smem);
        const int n0 = (b & 31) * 32, k0 = (b >> 5) * 32;
        const int r = tid >> 3, c4 = (tid & 7) * 4;
        float4 v = *reinterpret_cast<const float4*>(&W2[(size_t)(k0 + r) * 1024 + n0 + c4]);
        tile[r][c4 + 0] = v.x; tile[r][c4 + 1] = v.y;
        tile[r][c4 + 2] = v.z; tile[r][c4 + 3] = v.w;
        __syncthreads();
        h4_t o;
        o[0] = (_Float16)tile[c4 + 0][r]; o[1] = (_Float16)tile[c4 + 1][r];
        o[2] = (_Float16)tile[c4 + 2][r]; o[3] = (_Float16)tile[c4 + 3][r];
        *reinterpret_cast<h4_t*>(&W2T[(size_t)(n0 + r) * 1024 + k0 + c4]) = o;
    } else if (b < 3328) {                  // pack tail weights (K=32 B-frag)
        const int idx = (b - 1024) * 256 + tid;
        if (idx < 589824) {
            const int r = idx / 9216, qq = idx % 9216;
            float v;
            if (qq < 1024) {
                int nt = qq >> 8, rem = qq & 255, l = rem >> 2, j = rem & 3;
                int n = nt * 16 + (l & 15), k = (l >> 4) * 4 + j;
                v = a1W[(size_t)r * 1024 + k * 64 + n];
            } else if (qq < 5120) {
                int p = qq - 1024, kt = p >> 11, u = p & 2047, nt = u >> 9, s = u & 511,
                    l = s >> 3, j = s & 7;
                int n = nt * 16 + (l & 15), k = kt * 32 + (l >> 4) * 8 + j;
                v = a2W[(size_t)r * 4096 + k * 64 + n];
            } else {
                int p = qq - 5120, kt = p >> 11, u = p & 2047, nt = u >> 9, s = u & 511,
                    l = s >> 3, j = s & 7;
                int n = nt * 16 + (l & 15), k = kt * 32 + (l >> 4) * 8 + j;
                v = Wp2[((size_t)r * 64 + k) * 64 + n];
            }
            wpack[idx] = (_Float16)v;
        }
    } else if (b < 4352) {                  // WfT[n][k] = fp16 sum_j Wpca[k][j]W1[j][n]
        float (*Ws)[65]  = reinterpret_cast<float(*)[65]>(smem);          // Wpca rows (8320B)
        float (*W1s)[33] = reinterpret_cast<float(*)[33]>(smem + 8448);   // W1 cols  (8448B)
        const int b3 = b - 3328;
        const int n0 = (b3 & 31) * 32, k0 = (b3 >> 5) * 32;
        {
            const int r  = tid >> 3;            // 0..31
            const int j0 = (tid & 7) * 8;
            float4 v0 = *reinterpret_cast<const float4*>(&Wpca[(size_t)(k0 + r) * 64 + j0]);
            float4 v1 = *reinterpret_cast<const float4*>(&Wpca[(size_t)(k0 + r) * 64 + j0 + 4]);
            Ws[r][j0 + 0] = v0.x; Ws[r][j0 + 1] = v0.y; Ws[r][j0 + 2] = v0.z; Ws[r][j0 + 3] = v0.w;
            Ws[r][j0 + 4] = v1.x; Ws[r][j0 + 5] = v1.y; Ws[r][j0 + 6] = v1.z; Ws[r][j0 + 7] = v1.w;
            const int j  = tid >> 2;            // 0..63
            const int nq = (tid & 3) * 8;
            float4 w0 = *reinterpret_cast<const float4*>(&W1[(size_t)j * 1024 + n0 + nq]);
            float4 w1 = *reinterpret_cast<const float4*>(&W1[(size_t)j * 1024 + n0 + nq + 4]);
            W1s[j][nq + 0] = w0.x; W1s[j][nq + 1] = w0.y; W1s[j][nq + 2] = w0.z; W1s[j][nq + 3] = w0.w;
            W1s[j][nq + 4] = w1.x; W1s[j][nq + 5] = w1.y; W1s[j][nq + 6] = w1.z; W1s[j][nq + 7] = w1.w;
        }
        __syncthreads();
        const int nl = tid >> 3;            // 0..31
        const int kq = (tid & 7) * 4;
        float acc[4] = {0.f, 0.f, 0.f, 0.f};
#pragma unroll
        for (int j = 0; j < 64; ++j) {
            float wv = W1s[j][nl];
#pragma unroll
            for (int kk = 0; kk < 4; ++kk)
                acc[kk] = fmaf(Ws[kq + kk][j], wv, acc[kk]);
        }
        h4_t pk;
        pk[0] = (_Float16)acc[0]; pk[1] = (_Float16)acc[1];
        pk[2] = (_Float16)acc[2]; pk[3] = (_Float16)acc[3];
        *reinterpret_cast<h4_t*>(&WfT[(size_t)(n0 + nl) * 1024 + k0 + kq]) = pk;
    } else if (b < 6400) {                  // x16 = fp16(x)
        const size_t base = (size_t)(b - 4352) * 2048 + (size_t)tid * 8;
        float4 v0 = *reinterpret_cast<const float4*>(&x[base]);
        float4 v1 = *reinterpret_cast<const float4*>(&x[base + 4]);
        h8_t o;
        o[0] = (_Float16)v0.x; o[1] = (_Float16)v0.y; o[2] = (_Float16)v0.z; o[3] = (_Float16)v0.w;
        o[4] = (_Float16)v1.x; o[5] = (_Float16)v1.y; o[6] = (_Float16)v1.z; o[7] = (_Float16)v1.w;
        *reinterpret_cast<h8_t*>(&x16[base]) = o;
    } else if (b == 6400) {                 // bfused[n] = b1[n] + sum_j bpca[j]W1[j][n]
        const int n = tid * 4;
        float a0 = b1[n], a1v = b1[n + 1], a2v = b1[n + 2], a3 = b1[n + 3];
#pragma unroll
        for (int j = 0; j < 64; ++j) {
            float bp = bpca[j];
            a0  = fmaf(bp, W1[(size_t)j * 1024 + n + 0], a0);
            a1v = fmaf(bp, W1[(size_t)j * 1024 + n + 1], a1v);
            a2v = fmaf(bp, W1[(size_t)j * 1024 + n + 2], a2v);
            a3  = fmaf(bp, W1[(size_t)j * 1024 + n + 3], a3);
        }
        float4 o; o.x = a0; o.y = a1v; o.z = a2v; o.w = a3;
        *reinterpret_cast<float4*>(&bfused[n]) = o;
    } else {                                // out init with constant term
        const int idx = (b - 6401) * 256 + tid;
        float cst = bl[0];
#pragma unroll
        for (int f = 0; f < 64; ++f)
            cst += bp2[f] * Wl[f];
        out[idx] = cst;
    }
}

// ---------------------------------------------------------------------------
// K1: h1h = leaky(x16 @ Wf + bfused), LINEAR fp16 output.
// BM=64, BN=128, BK=64, grid (8,64) — proven v2 structure.
// ---------------------------------------------------------------------------
__global__ __launch_bounds__(256) void gemm_h1(const _Float16* __restrict__ A,
                                               const _Float16* __restrict__ BT,
                                               const float* __restrict__ bias,
                                               _Float16* __restrict__ C)
{
    __shared__ alignas(16) _Float16 As[64 * 64];
    __shared__ alignas(16) _Float16 Bs[128 * 64];
    const int tid = threadIdx.x;
    const int l   = tid & 63;
    const int w   = tid >> 6;
    const int wm  = w >> 1;
    const int wn  = w & 1;
    const int bm0 = blockIdx.y * 64;
    const int bn0 = blockIdx.x * 128;
    const int fr  = l & 15;
    const int fg  = l >> 4;
    const int srow  = l >> 3;
    const int sslot = l & 7;

    f32x4 acc[2][4] = {};

    for (int k0 = 0; k0 < 1024; k0 += 64) {
#pragma unroll
        for (int i = 0; i < 2; ++i) {
            const int r0   = w * 16 + i * 8;
            const int rowA = r0 + srow;
            const int slot = sslot ^ (rowA & 7);
            __builtin_amdgcn_global_load_lds(
                (const __attribute__((address_space(1))) void*)&A[(size_t)(bm0 + rowA) * 1024 + k0 + slot * 8],
                (__attribute__((address_space(3))) void*)&As[r0 * 64], 16, 0, 0);
        }
#pragma unroll
        for (int i = 0; i < 4; ++i) {
            const int r0   = w * 32 + i * 8;
            const int rowB = r0 + srow;
            const int slot = sslot ^ (rowB & 7);
            __builtin_amdgcn_global_load_lds(
                (const __attribute__((address_space(1))) void*)&BT[(size_t)(bn0 + rowB) * 1024 + k0 + slot * 8],
                (__attribute__((address_space(3))) void*)&Bs[r0 * 64], 16, 0, 0);
        }
        __syncthreads();

#pragma unroll
        for (int ks = 0; ks < 2; ++ks) {
            h8_t af[2], bf[4];
#pragma unroll
            for (int mt = 0; mt < 2; ++mt) {
                int row = wm * 32 + mt * 16 + fr;
                int sg  = ks * 4 + fg;
                af[mt] = *reinterpret_cast<const h8_t*>(&As[row * 64 + ((sg ^ (row & 7)) << 3)]);
            }
#pragma unroll
            for (int nt = 0; nt < 4; ++nt) {
                int row = wn * 64 + nt * 16 + fr;
                int sg  = ks * 4 + fg;
                bf[nt] = *reinterpret_cast<const h8_t*>(&Bs[row * 64 + ((sg ^ (row & 7)) << 3)]);
            }
#pragma unroll
            for (int mt = 0; mt < 2; ++mt)
#pragma unroll
                for (int nt = 0; nt < 4; ++nt)
                    acc[mt][nt] = __builtin_amdgcn_mfma_f32_16x16x32_f16(af[mt], bf[nt],
                                                                         acc[mt][nt], 0, 0, 0);
        }
        __syncthreads();
    }

#pragma unroll
    for (int nt = 0; nt < 4; ++nt) {
        const int col = bn0 + wn * 64 + nt * 16 + fr;
        const float bv = bias[col];
#pragma unroll
        for (int mt = 0; mt < 2; ++mt)
#pragma unroll
            for (int rg = 0; rg < 4; ++rg) {
                const int row = bm0 + wm * 32 + mt * 16 + fg * 4 + rg;
                float v = acc[mt][nt][rg] + bv;
                C[(size_t)row * 1024 + col] = (_Float16)fmaxf(v, NEG_SLOPE * v);
            }
    }
}

// ---------------------------------------------------------------------------
// K2: h2t = pack(leaky(h1 @ W2 + b2)). (unchanged proven v2)
// ---------------------------------------------------------------------------
__global__ __launch_bounds__(256) void gemm_mfma_f16_v2(const _Float16* __restrict__ A,
                                                        const _Float16* __restrict__ BT,
                                                        const float* __restrict__ bias,
                                                        _Float16* __restrict__ h2t)
{
    __shared__ alignas(16) _Float16 As[64 * 64];
    __shared__ alignas(16) _Float16 Bs[128 * 64];
    const int tid = threadIdx.x;
    const int l   = tid & 63;
    const int w   = tid >> 6;
    const int wm  = w >> 1;
    const int wn  = w & 1;
    const int bm0 = blockIdx.y * 64;
    const int bn0 = blockIdx.x * 128;
    const int fr  = l & 15;
    const int fg  = l >> 4;
    const int srow  = l >> 3;
    const int sslot = l & 7;

    f32x4 acc[2][4] = {};

    for (int k0 = 0; k0 < 1024; k0 += 64) {
#pragma unroll
        for (int i = 0; i < 2; ++i) {
            const int r0   = w * 16 + i * 8;
            const int rowA = r0 + srow;
            const int slot = sslot ^ (rowA & 7);
            __builtin_amdgcn_global_load_lds(
                (const __attribute__((address_space(1))) void*)&A[(size_t)(bm0 + rowA) * 1024 + k0 + slot * 8],
                (__attribute__((address_space(3))) void*)&As[r0 * 64], 16, 0, 0);
        }
#pragma unroll
        for (int i = 0; i < 4; ++i) {
            const int r0   = w * 32 + i * 8;
            const int rowB = r0 + srow;
            const int slot = sslot ^ (rowB & 7);
            __builtin_amdgcn_global_load_lds(
                (const __attribute__((address_space(1))) void*)&BT[(size_t)(bn0 + rowB) * 1024 + k0 + slot * 8],
                (__attribute__((address_space(3))) void*)&Bs[r0 * 64], 16, 0, 0);
        }
        __syncthreads();

#pragma unroll
        for (int ks = 0; ks < 2; ++ks) {
            h8_t af[2], bf[4];
#pragma unroll
            for (int mt = 0; mt < 2; ++mt) {
                int row = wm * 32 + mt * 16 + fr;
                int sg  = ks * 4 + fg;
                af[mt] = *reinterpret_cast<const h8_t*>(&As[row * 64 + ((sg ^ (row & 7)) << 3)]);
            }
#pragma unroll
            for (int nt = 0; nt < 4; ++nt) {
                int row = wn * 64 + nt * 16 + fr;
                int sg  = ks * 4 + fg;
                bf[nt] = *reinterpret_cast<const h8_t*>(&Bs[row * 64 + ((sg ^ (row & 7)) << 3)]);
            }
#pragma unroll
            for (int mt = 0; mt < 2; ++mt)
#pragma unroll
                for (int nt = 0; nt < 4; ++nt)
                    acc[mt][nt] = __builtin_amdgcn_mfma_f32_16x16x32_f16(af[mt], bf[nt],
                                                                         acc[mt][nt], 0, 0, 0);
        }
        __syncthreads();
    }

    const int rblk0 = (bm0 >> 4) + wm * 2;
    const int cblk0 = (bn0 >> 4) + wn * 4;
#pragma unroll
    for (int nt = 0; nt < 4; ++nt) {
        const int col = bn0 + wn * 64 + nt * 16 + fr;
        const float bv = bias[col];
#pragma unroll
        for (int mt = 0; mt < 2; ++mt) {
            h4_t pk;
#pragma unroll
            for (int r = 0; r < 4; ++r) {
                float v = acc[mt][nt][r] + bv;
                pk[r] = (_Float16)fmaxf(v, NEG_SLOPE * v);
            }
            *reinterpret_cast<h4_t*>(
                &h2t[(((size_t)(cblk0 + nt) * 256 + rblk0 + mt) * 16 + fr) * 16 + fg * 4]) = pk;
        }
    }
}

// ---------------------------------------------------------------------------
// K3: fused additive chain v5b (unchanged from passing round 15).
// ---------------------------------------------------------------------------
__global__ __launch_bounds__(256) void fused_tail5b(const _Float16* __restrict__ h2t,
                                                    const _Float16* __restrict__ wpack,
                                                    const float* __restrict__ a1b,
                                                    const float* __restrict__ a1bias,
                                                    const float* __restrict__ a2b,
                                                    const float* __restrict__ a2bias,
                                                    const float* __restrict__ Wl,
                                                    float* __restrict__ out)
{
    __shared__ alignas(16) _Float16 stage[2][11264];  // 2 x 22KB
    __shared__ alignas(16) _Float16 act[4][2048];     // per-wave, 2 tiles (16KB)

    const int tid = threadIdx.x;
    const int l = tid & 63, w = tid >> 6;
    const int c = l & 15, q = l >> 4;
    const int row0  = blockIdx.x * 128;
    const int rbase = blockIdx.y * RCH;
    const float b1s = a1bias[0], b2s = a2bias[0];

    const unsigned trl   = l * 8;
    const unsigned abase = lds_off(&act[w][0]);

    float b1v[RCH][4], b2v[RCH][4];
#pragma unroll
    for (int rl = 0; rl < RCH; ++rl)
#pragma unroll
        for (int nt = 0; nt < 4; ++nt) {
            b1v[rl][nt] = a1b[(rbase + rl) * 64 + nt * 16 + c] + b1s;
            b2v[rl][nt] = a2b[(rbase + rl) * 64 + nt * 16 + c] + b2s;
        }
    float wlv[4];
#pragma unroll
    for (int nt = 0; nt < 4; ++nt) wlv[nt] = Wl[nt * 16 + c];

    auto STAGE = [&](int rl, int b) {
        const int r = rbase + rl;
        const _Float16* hsrc = h2t + ((size_t)r * 256 + blockIdx.x * 8) * 256;
        const _Float16* wsrc = wpack + (size_t)r * 9216;
#pragma unroll
        for (int i = 0; i < 6; ++i) {
            const int ch = i * 4 + w;
            if (ch < 22) {
                const _Float16* src = (ch < 4) ? (hsrc + ch * 512) : (wsrc + (ch - 4) * 512);
                __builtin_amdgcn_global_load_lds(
                    (const __attribute__((address_space(1))) void*)(src + l * 8),
                    (__attribute__((address_space(3))) void*)&stage[b][ch * 512], 16, 0, 0);
            }
        }
    };

    STAGE(0, 0);
    __syncthreads();

    f32x4 accT[2][4] = {};
    int cur = 0;

#pragma unroll
    for (int rl = 0; rl < RCH; ++rl) {
        if (rl + 1 < RCH) STAGE(rl + 1, cur ^ 1);

        const _Float16* sp = &stage[cur][0];
        const unsigned sbytes = lds_off(sp);

        // ---- phase A
        h4_t ha0 = tr16(sbytes + (unsigned)(w) * 512 + trl);
        h4_t ha1 = tr16(sbytes + (unsigned)(w + 4) * 512 + trl);
        lgkm0();
        f32x4 pa[2][4];
#pragma unroll
        for (int nt = 0; nt < 4; ++nt) {
            h4_t bf = *reinterpret_cast<const h4_t*>(&sp[2048 + nt * 256 + l * 4]);
            pa[0][nt] = __builtin_amdgcn_mfma_f32_16x16x16f16(ha0, bf, (f32x4){0.f,0.f,0.f,0.f}, 0, 0, 0);
            pa[1][nt] = __builtin_amdgcn_mfma_f32_16x16x16f16(ha1, bf, (f32x4){0.f,0.f,0.f,0.f}, 0, 0, 0);
        }
#pragma unroll
        for (int j = 0; j < 2; ++j)
#pragma unroll
            for (int nt = 0; nt < 4; ++nt) {
                h4_t pk;
#pragma unroll
                for (int rg = 0; rg < 4; ++rg) {
                    float v = pa[j][nt][rg] + b1v[rl][nt];
                    pk[rg] = (_Float16)fmaxf(v, NEG_SLOPE * v);
                }
                const int kk = nt * 16 + c;
                const int hh = (kk >> 2) & 1;
                const int kp = (kk & 3) | ((kk >> 3) << 2);
                *reinterpret_cast<h4_t*>(&act[w][j * 1024 + hh * 512 + kp * 16 + q * 4]) = pk;
            }
        lgkm0();

        // ---- phase B
        h8_t afB[2][2];
#pragma unroll
        for (int j = 0; j < 2; ++j)
#pragma unroll
            for (int kt = 0; kt < 2; ++kt) {
                h4_t lo = tr16(abase + (unsigned)(j * 2048 + kt * 512) + trl);
                h4_t hi = tr16(abase + (unsigned)(j * 2048 + 1024 + kt * 512) + trl);
                afB[j][kt] = __builtin_shufflevector(lo, hi, 0, 1, 2, 3, 4, 5, 6, 7);
            }
        lgkm0();
        f32x4 pb[2][4] = {};
#pragma unroll
        for (int kt = 0; kt < 2; ++kt)
#pragma unroll
            for (int nt = 0; nt < 4; ++nt) {
                h8_t bf = *reinterpret_cast<const h8_t*>(&sp[3072 + kt * 2048 + nt * 512 + l * 8]);
                pb[0][nt] = __builtin_amdgcn_mfma_f32_16x16x32_f16(afB[0][kt], bf, pb[0][nt], 0, 0, 0);
                pb[1][nt] = __builtin_amdgcn_mfma_f32_16x16x32_f16(afB[1][kt], bf, pb[1][nt], 0, 0, 0);
            }
#pragma unroll
        for (int j = 0; j < 2; ++j)
#pragma unroll
            for (int nt = 0; nt < 4; ++nt) {
                h4_t pk;
#pragma unroll
                for (int rg = 0; rg < 4; ++rg) {
                    float v = pb[j][nt][rg] + b2v[rl][nt];
                    pk[rg] = (_Float16)fmaxf(v, NEG_SLOPE * v);
                }
                const int kk = nt * 16 + c;
                const int hh = (kk >> 2) & 1;
                const int kp = (kk & 3) | ((kk >> 3) << 2);
                *reinterpret_cast<h4_t*>(&act[w][j * 1024 + hh * 512 + kp * 16 + q * 4]) = pk;
            }
        lgkm0();

        // ---- phase C
        h8_t afC[2][2];
#pragma unroll
        for (int j = 0; j < 2; ++j)
#pragma unroll
            for (int kt = 0; kt < 2; ++kt) {
                h4_t lo = tr16(abase + (unsigned)(j * 2048 + kt * 512) + trl);
                h4_t hi = tr16(abase + (unsigned)(j * 2048 + 1024 + kt * 512) + trl);
                afC[j][kt] = __builtin_shufflevector(lo, hi, 0, 1, 2, 3, 4, 5, 6, 7);
            }
        lgkm0();
#pragma unroll
        for (int kt = 0; kt < 2; ++kt)
#pragma unroll
            for (int nt = 0; nt < 4; ++nt) {
                h8_t bf = *reinterpret_cast<const h8_t*>(&sp[7168 + kt * 2048 + nt * 512 + l * 8]);
                accT[0][nt] = __builtin_amdgcn_mfma_f32_16x16x32_f16(afC[0][kt], bf, accT[0][nt], 0, 0, 0);
                accT[1][nt] = __builtin_amdgcn_mfma_f32_16x16x32_f16(afC[1][kt], bf, accT[1][nt], 0, 0, 0);
            }

        __syncthreads();
        cur ^= 1;
    }

    // ---- epilogue: per-row dot with Wl, lane-reduce, atomicAdd
#pragma unroll
    for (int j = 0; j < 2; ++j)
#pragma unroll
        for (int rg = 0; rg < 4; ++rg) {
            float s = accT[j][0][rg] * wlv[0] + accT[j][1][rg] * wlv[1] +
                      accT[j][2][rg] * wlv[2] + accT[j][3][rg] * wlv[3];
            s += __shfl_xor(s, 1);
            s += __shfl_xor(s, 2);
            s += __shfl_xor(s, 4);
            s += __shfl_xor(s, 8);
            if (c == 0) {
                const int row = row0 + (w + 4 * j) * 16 + q * 4 + rg;
                atomicAdd(&out[row], s);
            }
        }
}

// ---------------------------------------------------------------------------
extern "C" void kernel_launch(void* const* d_in, const int* in_sizes, int n_in,
                              void* d_out, int out_size, void* d_ws, size_t ws_size,
                              hipStream_t stream)
{
    const float* x      = (const float*)d_in[0];
    const float* Wpca   = (const float*)d_in[1];
    const float* bpca   = (const float*)d_in[2];
    const float* W1     = (const float*)d_in[3];
    const float* b1     = (const float*)d_in[4];
    const float* W2     = (const float*)d_in[5];
    const float* b2     = (const float*)d_in[6];
    const float* a1W    = (const float*)d_in[7];
    const float* a1b    = (const float*)d_in[8];
    const float* a1bias = (const float*)d_in[9];
    const float* a2W    = (const float*)d_in[10];
    const float* a2b    = (const float*)d_in[11];
    const float* a2bias = (const float*)d_in[12];
    const float* Wp2    = (const float*)d_in[13];
    const float* bp2    = (const float*)d_in[14];
    const float* Wl     = (const float*)d_in[15];
    const float* bl     = (const float*)d_in[16];
    float* out = (float*)d_out;

    // workspace layout (bytes) — fully disjoint:
    //   x16 [0,8M)  h1h [8M,16M)  h2t [16M,24M)  W2T [24M,26M)
    //   wpack [26M,27.13M)  WfT [28M,30M)  bfused [30.5M,+4KB)
    char* wsb = (char*)d_ws;
    _Float16* x16    = (_Float16*)(wsb);
    _Float16* h1h    = (_Float16*)(wsb + (8ull  << 20));
    _Float16* h2t    = (_Float16*)(wsb + (16ull << 20));
    _Float16* W2T    = (_Float16*)(wsb + (24ull << 20));
    _Float16* wpack  = (_Float16*)(wsb + (26ull << 20));
    _Float16* WfT    = (_Float16*)(wsb + (28ull << 20));
    float*    bfused = (float*)   (wsb + (30ull << 20) + (512ull << 10));

    // K0: all prep in one launch (W2T || wpack || WfT || x16 || bfused || out)
    prep2<<<dim3(6417), 256, 0, stream>>>(W2, W1, Wpca, bpca, b1, a1W, a2W, Wp2,
                                          x, bp2, Wl, bl,
                                          W2T, wpack, WfT, x16, bfused, out);
    // K1: h1 = leaky(x @ (Wpca@W1) + bfused)  — fused PCA1+NN1, MFMA
    gemm_h1<<<dim3(8, 64), 256, 0, stream>>>(x16, WfT, bfused, h1h);
    // K2: h2 (packed) = leaky(h1 @ W2 + b2) via MFMA
    gemm_mfma_f16_v2<<<dim3(8, 64), 256, 0, stream>>>(h1h, W2T, b2, h2t);
    // K3: fused additive chain -> atomicAdd into out
    fused_tail5b<<<dim3(32, 16), 256, 0, stream>>>(h2t, wpack, a1b, a1bias,
                                                   a2b, a2bias, Wl, out);
}